// Round 7
// baseline (2234.396 us; speedup 1.0000x reference)
//
#include <hip/hip_runtime.h>
#include <math.h>

#define NTOK 262144
#define DIM  256
#define NH   8
#define CH   32
#define NS   64

typedef __attribute__((ext_vector_type(8))) short short8v;   // 8 bf16 = 4 VGPR
typedef __attribute__((ext_vector_type(4))) short short4v;   // 4 bf16 = 2 VGPR
typedef __attribute__((ext_vector_type(4))) float float4v;

// ---------------- workspace layout (bytes) ----------------
constexpr size_t OFF_MIDFX = 0;                          // 256*N bf16 ch-major = 134217728
constexpr size_t OFF_MIDXM = 134217728;                  // N*256 bf16 tok-major = 134217728
constexpr size_t OFF_WCT   = 268435456;                  // 512*256 bf16 = 262144
constexpr size_t OFF_WPT   = OFF_WCT + 262144;           // 256*256 bf16 = 131072
constexpr size_t OFF_POOLP = OFF_WPT + 131072;           // 512*16384 f32 = 33554432
constexpr size_t OFF_NORMP = OFF_POOLP + 33554432;       // 512*512 f32 = 1048576
constexpr size_t OFF_SSUM  = OFF_NORMP + 1048576;        // 16384 f32
constexpr size_t OFF_NSUM  = OFF_SSUM + 65536;           // 512 f32
constexpr size_t OFF_OSL   = OFF_NSUM + 2048;            // 16384 f32

#define KA_LDS_B 81920                       // A 128x64 (16KB) + B 512x64 (64KB): 2 blk/CU
#define KB_LDS_F (17408 + 2048 + 64)         // wls[512][34] + Wslc + bsl = 78080B: 2 blk/CU
#define KD_LDS_B 139648                      // oslds+wsl+bsl + atile 32KB + btile 32KB

__device__ __forceinline__ unsigned short f2bf(float f) {
    unsigned u = __float_as_uint(f);
    unsigned r = (u + 0x7fffu + ((u >> 16) & 1u)) >> 16;   // RNE
    return (unsigned short)r;
}
__device__ __forceinline__ float bf2f(unsigned short u) {
    return __uint_as_float(((unsigned)u) << 16);
}

// ---- logits+softmax from bf16 x_mid row (token-major, stride 256) ----
__device__ __forceinline__ void compute_w_bf(const unsigned short* __restrict__ xm,
                                             const float* __restrict__ wsl,
                                             const float* __restrict__ bsl,
                                             float invT, float* lg)
{
    float xv[32];
    #pragma unroll
    for (int q = 0; q < 4; ++q) {
        const uint4 u = *(const uint4*)(xm + q*8);
        const unsigned vals[4] = {u.x, u.y, u.z, u.w};
        #pragma unroll
        for (int j = 0; j < 4; ++j) {
            xv[q*8 + j*2 + 0] = __uint_as_float(vals[j] << 16);
            xv[q*8 + j*2 + 1] = __uint_as_float(vals[j] & 0xffff0000u);
        }
    }
    #pragma unroll
    for (int s = 0; s < 64; ++s) lg[s] = bsl[s];
    #pragma unroll
    for (int c = 0; c < 32; ++c) {
        const float xvj = xv[c];
        const float* wr = wsl + c*64;
        #pragma unroll
        for (int s4 = 0; s4 < 16; ++s4) {
            const float4 w4 = *(const float4*)(wr + s4*4);
            lg[s4*4+0] = fmaf(xvj, w4.x, lg[s4*4+0]);
            lg[s4*4+1] = fmaf(xvj, w4.y, lg[s4*4+1]);
            lg[s4*4+2] = fmaf(xvj, w4.z, lg[s4*4+2]);
            lg[s4*4+3] = fmaf(xvj, w4.w, lg[s4*4+3]);
        }
    }
    float m = -1e30f;
    #pragma unroll
    for (int s = 0; s < 64; ++s) { lg[s] *= invT; m = fmaxf(m, lg[s]); }
    float sum = 0.f;
    #pragma unroll
    for (int s = 0; s < 64; ++s) { lg[s] = expf(lg[s] - m); sum += lg[s]; }
    const float r = 1.0f / sum;
    #pragma unroll
    for (int s = 0; s < 64; ++s) lg[s] *= r;
}

__device__ __forceinline__ void scat_acc(const float* __restrict__ orow, float wv, float* ox)
{
    #pragma unroll
    for (int c4 = 0; c4 < 8; ++c4) {
        const float4 o4 = *(const float4*)(orow + c4*4);
        ox[c4*4+0] = fmaf(wv, o4.x, ox[c4*4+0]);
        ox[c4*4+1] = fmaf(wv, o4.y, ox[c4*4+1]);
        ox[c4*4+2] = fmaf(wv, o4.z, ox[c4*4+2]);
        ox[c4*4+3] = fmaf(wv, o4.w, ox[c4*4+3]);
    }
}

// =========================================================================
// kW: convert weights to bf16, transposed. WcatT[512][256] = [Wfx|Wx]^T,
//     WprojT[256][256] = Wproj^T. Grid 24 x 512.
// =========================================================================
__global__ void __launch_bounds__(512) tk_w(
    const float* __restrict__ Wfx, const float* __restrict__ Wx,
    const float* __restrict__ Wproj,
    unsigned short* __restrict__ WcatT, unsigned short* __restrict__ WprojT)
{
    const int t = threadIdx.x, b = blockIdx.x;
    const int rl = t >> 4, q = t & 15;      // row-in-block, k-quarter
    if (b < 16) {
        const int r = b*32 + rl;            // 0..511
        #pragma unroll
        for (int j = 0; j < 16; ++j) {
            const int k = q*16 + j;
            const float v = (r < 256) ? Wfx[(size_t)k*256 + r] : Wx[(size_t)k*256 + (r-256)];
            WcatT[(size_t)r*256 + k] = f2bf(v);
        }
    } else {
        const int r = (b-16)*32 + rl;       // 0..255
        #pragma unroll
        for (int j = 0; j < 16; ++j) {
            const int k = q*16 + j;
            WprojT[(size_t)r*256 + k] = f2bf(Wproj[(size_t)k*256 + r]);
        }
    }
}

// =========================================================================
// kA: fx/xm = x @ [Wfx|Wx] + bias via 16x16x32 bf16 MFMA.
//     fx (cols 0..255)  -> midfx[c][n]  channel-major (waves wn=0,1)
//     xm (cols 256..511)-> midxm[n][c]  token-major   (waves wn=2,3)
//     2048 blocks x 512 thr; tile 128 x 512, K=256 in 4 chunks of 64.
// =========================================================================
__global__ void __launch_bounds__(512, 2) tk_a(
    const float* __restrict__ x,
    const unsigned short* __restrict__ WcatT,
    const float* __restrict__ bfx, const float* __restrict__ bx,
    unsigned short* __restrict__ midfx, unsigned short* __restrict__ midxm)
{
    extern __shared__ char smem[];
    char* astage = smem;              // [128][64] bf16, swizzled
    char* bstage = smem + 16384;      // [512][64] bf16, swizzled

    const int t = threadIdx.x;
    const int l = t & 63, w = t >> 6;
    const int wm = w >> 2, wn = w & 3;
    const int m0 = blockIdx.x * 128;

    float4v acc[4][8];
    #pragma unroll
    for (int mr = 0; mr < 4; ++mr)
        #pragma unroll
        for (int nr = 0; nr < 8; ++nr)
            acc[mr][nr] = (float4v){0.f, 0.f, 0.f, 0.f};

    const int ar = t >> 2, aq = t & 3;      // A-stage: row, k-quarter(16)

    for (int c = 0; c < 4; ++c) {
        // ---- stage A: x[m0..m0+127][c*64..+64] fp32 -> bf16 LDS ----
        {
            const float* xr = x + (size_t)(m0 + ar)*256 + c*64 + aq*16;
            const float4 f0 = *(const float4*)(xr + 0);
            const float4 f1 = *(const float4*)(xr + 4);
            const float4 f2 = *(const float4*)(xr + 8);
            const float4 f3 = *(const float4*)(xr + 12);
            short8v v0, v1;
            v0[0]=(short)f2bf(f0.x); v0[1]=(short)f2bf(f0.y); v0[2]=(short)f2bf(f0.z); v0[3]=(short)f2bf(f0.w);
            v0[4]=(short)f2bf(f1.x); v0[5]=(short)f2bf(f1.y); v0[6]=(short)f2bf(f1.z); v0[7]=(short)f2bf(f1.w);
            v1[0]=(short)f2bf(f2.x); v1[1]=(short)f2bf(f2.y); v1[2]=(short)f2bf(f2.z); v1[3]=(short)f2bf(f2.w);
            v1[4]=(short)f2bf(f3.x); v1[5]=(short)f2bf(f3.y); v1[6]=(short)f2bf(f3.z); v1[7]=(short)f2bf(f3.w);
            const int ob = ar*128 + aq*32;
            *(short8v*)(astage + ((ob     ) ^ ((ar & 7) << 4))) = v0;
            *(short8v*)(astage + ((ob + 16) ^ ((ar & 7) << 4))) = v1;
        }
        // ---- stage B: WcatT[n][c*64..+64] -> LDS (already bf16) ----
        {
            const int n = t;
            #pragma unroll
            for (int j = 0; j < 8; ++j) {
                const uint4 u = *(const uint4*)(WcatT + (size_t)n*256 + c*64 + j*8);
                *(uint4*)(bstage + ((n*128 + j*16) ^ ((n & 7) << 4))) = u;
            }
        }
        __syncthreads();
        #pragma unroll
        for (int ks = 0; ks < 2; ++ks) {
            short8v a[4], b[8];
            const int kof = (ks*32 + (l >> 4)*8) * 2;
            #pragma unroll
            for (int mr = 0; mr < 4; ++mr) {
                const int m = wm*64 + mr*16 + (l & 15);
                a[mr] = *(const short8v*)(astage + ((m*128 + kof) ^ ((m & 7) << 4)));
            }
            #pragma unroll
            for (int nr = 0; nr < 8; ++nr) {
                const int n = wn*128 + nr*16 + (l & 15);
                b[nr] = *(const short8v*)(bstage + ((n*128 + kof) ^ ((n & 7) << 4)));
            }
            #pragma unroll
            for (int mr = 0; mr < 4; ++mr)
                #pragma unroll
                for (int nr = 0; nr < 8; ++nr)
                    acc[mr][nr] = __builtin_amdgcn_mfma_f32_16x16x32_bf16(
                        a[mr], b[nr], acc[mr][nr], 0, 0, 0);
        }
        __syncthreads();
    }

    // ---- epilogue: + bias, cvt bf16, store ----
    if (wn < 2) {
        // fx part: col 0..255, channel-major store, 4 consecutive tokens / frag
        float bias_n[8];
        #pragma unroll
        for (int nr = 0; nr < 8; ++nr) bias_n[nr] = bfx[wn*128 + nr*16 + (l & 15)];
        #pragma unroll
        for (int mr = 0; mr < 4; ++mr) {
            const int row0 = m0 + wm*64 + mr*16 + (l >> 4)*4;
            #pragma unroll
            for (int nr = 0; nr < 8; ++nr) {
                const int col = wn*128 + nr*16 + (l & 15);
                const float bv = bias_n[nr];
                short4v p;
                p[0] = (short)f2bf(acc[mr][nr][0] + bv);
                p[1] = (short)f2bf(acc[mr][nr][1] + bv);
                p[2] = (short)f2bf(acc[mr][nr][2] + bv);
                p[3] = (short)f2bf(acc[mr][nr][3] + bv);
                *(short4v*)(midfx + (size_t)col*NTOK + row0) = p;
            }
        }
    } else {
        // xm part: col 256..511 -> midxm[n][col-256], token-major store
        float bias_n[8];
        #pragma unroll
        for (int nr = 0; nr < 8; ++nr) bias_n[nr] = bx[(wn-2)*128 + nr*16 + (l & 15)];
        #pragma unroll
        for (int mr = 0; mr < 4; ++mr) {
            #pragma unroll
            for (int reg = 0; reg < 4; ++reg) {
                const int row = m0 + wm*64 + mr*16 + (l >> 4)*4 + reg;
                #pragma unroll
                for (int nr = 0; nr < 8; ++nr) {
                    const int col = (wn-2)*128 + nr*16 + (l & 15);
                    midxm[(size_t)row*256 + col] = f2bf(acc[mr][nr][reg] + bias_n[nr]);
                }
            }
        }
    }
}

// =========================================================================
// kB: logits+softmax+pool partials. 512 blocks x 8 tiles x 64 tokens.
//     fx from midfx (ch-major, 64B contiguous/thread), xm from midxm.
// =========================================================================
__global__ void __launch_bounds__(512, 2) tk_b(
    const unsigned short* __restrict__ midfx,
    const unsigned short* __restrict__ midxm,
    const float* __restrict__ Wslc, const float* __restrict__ bslc,
    const float* __restrict__ temp,
    float* __restrict__ poolp, float* __restrict__ normp)
{
    extern __shared__ float sm[];
    float* wls = sm;            // [512 rows][34]  (17408 f)
    float* wsl = sm + 17408;    // W_slice [32][64]
    float* bsl = wsl + 2048;    // b_slice [64]

    const int t   = threadIdx.x;
    const int blk = blockIdx.x;

    for (int i = t; i < 2048; i += 512) wsl[i] = Wslc[i];
    if (t < 64) bsl[t] = bslc[t];
    __syncthreads();

    const int cg = t & 255, ihalf = t >> 8;     // pool role
    const int hP = cg >> 5;
    const int cP = cg & 31;
    const int iL = t >> 3,   hL = t & 7;        // logits role
    const int hN = t >> 6;                      // norm role
    const int sN = (t >> 1) & 31, iqN = t & 1;

    float pool[64];
    #pragma unroll
    for (int s = 0; s < 64; ++s) pool[s] = 0.f;
    float nacc0 = 0.f, nacc1 = 0.f;

    const float invT = 1.0f / temp[hL];

    for (int tl = 0; tl < 8; ++tl) {
        const int n0 = blk*512 + tl*64;

        // fx for pool role: channel cg, 32 consecutive tokens (contiguous 64B)
        float afx[32];
        {
            const unsigned short* fr = midfx + (size_t)cg*NTOK + n0 + ihalf*32;
            #pragma unroll
            for (int q = 0; q < 4; ++q) {
                const uint4 u = *(const uint4*)(fr + q*8);
                const unsigned vals[4] = {u.x, u.y, u.z, u.w};
                #pragma unroll
                for (int j = 0; j < 4; ++j) {
                    afx[q*8 + j*2 + 0] = __uint_as_float(vals[j] << 16);
                    afx[q*8 + j*2 + 1] = __uint_as_float(vals[j] & 0xffff0000u);
                }
            }
        }

        // logits + softmax for (token iL, head hL)
        float lg[64];
        compute_w_bf(midxm + (size_t)(n0 + iL)*256 + hL*32, wsl, bsl, invT, lg);

        #pragma unroll
        for (int sh = 0; sh < 2; ++sh) {
            float* wrow = wls + t*34;
            #pragma unroll
            for (int sl = 0; sl < 32; sl += 2)
                *(float2*)(wrow + sl) = make_float2(lg[sh*32+sl], lg[sh*32+sl+1]);
            __syncthreads();
            #pragma unroll
            for (int ii = 0; ii < 32; ++ii) {
                const float fxv = afx[ii];
                const float* wr2 = wls + ((ihalf*32+ii)*8 + hP)*34;
                #pragma unroll
                for (int s8 = 0; s8 < 16; ++s8) {
                    const float2 w2 = *(const float2*)(wr2 + s8*2);
                    pool[sh*32+s8*2+0] = fmaf(fxv, w2.x, pool[sh*32+s8*2+0]);
                    pool[sh*32+s8*2+1] = fmaf(fxv, w2.y, pool[sh*32+s8*2+1]);
                }
            }
            {
                float na = 0.f;
                #pragma unroll
                for (int ii = 0; ii < 32; ++ii)
                    na += wls[((iqN*32+ii)*8 + hN)*34 + sN];
                if (sh == 0) nacc0 += na; else nacc1 += na;
            }
            __syncthreads();
        }
    }

    // ---- finalize: combine halves, write per-block partials ----
    if (ihalf == 1) {
        float* buf = wls + cg*65;                 // [256][65] region (16640 f)
        #pragma unroll
        for (int s = 0; s < 64; ++s) buf[s] = pool[s];
    }
    if (iqN == 1) {
        wls[16640 + (hN*32+sN)*2 + 0] = nacc0;
        wls[16640 + (hN*32+sN)*2 + 1] = nacc1;
    }
    __syncthreads();
    if (ihalf == 0) {
        const float* buf = wls + cg*65;
        float* dst = poolp + (size_t)blk*(NH*NS*CH) + (size_t)hP*(NS*CH) + cP;
        #pragma unroll
        for (int s = 0; s < 64; ++s) dst[(size_t)s*CH] = pool[s] + buf[s];
    }
    if (iqN == 0) {
        const float v0 = nacc0 + wls[16640 + (hN*32+sN)*2 + 0];
        const float v1 = nacc1 + wls[16640 + (hN*32+sN)*2 + 1];
        normp[(size_t)blk*512 + hN*64 + sN]      = v0;
        normp[(size_t)blk*512 + hN*64 + 32 + sN] = v1;
    }
}

// =========================================================================
// k2a: reduce 512 per-block partials -> slice sums + norms
// =========================================================================
__global__ void __launch_bounds__(256) tk_2a(
    const float* __restrict__ poolp, const float* __restrict__ normp,
    float* __restrict__ ssum, float* __restrict__ nsum)
{
    const int idx = blockIdx.x*256 + threadIdx.x;
    if (idx < 16384) {
        float a0=0.f,a1=0.f,a2=0.f,a3=0.f;
        for (int b = 0; b < 512; b += 4) {
            a0 += poolp[(size_t)(b+0)*16384 + idx];
            a1 += poolp[(size_t)(b+1)*16384 + idx];
            a2 += poolp[(size_t)(b+2)*16384 + idx];
            a3 += poolp[(size_t)(b+3)*16384 + idx];
        }
        ssum[idx] = (a0+a1)+(a2+a3);
    } else if (idx < 16896) {
        const int j = idx - 16384;
        float a0=0.f,a1=0.f,a2=0.f,a3=0.f;
        for (int b = 0; b < 512; b += 4) {
            a0 += normp[(size_t)(b+0)*512 + j];
            a1 += normp[(size_t)(b+1)*512 + j];
            a2 += normp[(size_t)(b+2)*512 + j];
            a3 += normp[(size_t)(b+3)*512 + j];
        }
        nsum[j] = (a0+a1)+(a2+a3);
    }
}

// =========================================================================
// k2b: slice tokens -> qkv -> SDPA over S=64 -> out_slice. 1 block/head.
// =========================================================================
__global__ void __launch_bounds__(64) tk_2b(
    const float* __restrict__ ssum, const float* __restrict__ nsum,
    const float* __restrict__ Wqkv, float* __restrict__ osl)
{
    __shared__ float ks[64*36];
    __shared__ float vs[64*36];
    const int h = blockIdx.x;
    const int s = threadIdx.x;

    const float inv = 1.0f / (nsum[h*64 + s] + 1e-5f);
    const float* st = ssum + h*2048 + s*32;

    float q[32], kk[32], vv[32];
    #pragma unroll
    for (int j = 0; j < 32; ++j) { q[j]=0.f; kk[j]=0.f; vv[j]=0.f; }
    for (int c = 0; c < 32; ++c) {
        const float sv = st[c] * inv;
        const float* wr = Wqkv + c*96;
        #pragma unroll
        for (int j4 = 0; j4 < 8; ++j4) {
            const float4 a = *(const float4*)(wr + j4*4);
            q[j4*4+0]=fmaf(sv,a.x,q[j4*4+0]); q[j4*4+1]=fmaf(sv,a.y,q[j4*4+1]);
            q[j4*4+2]=fmaf(sv,a.z,q[j4*4+2]); q[j4*4+3]=fmaf(sv,a.w,q[j4*4+3]);
            const float4 b = *(const float4*)(wr + 32 + j4*4);
            kk[j4*4+0]=fmaf(sv,b.x,kk[j4*4+0]); kk[j4*4+1]=fmaf(sv,b.y,kk[j4*4+1]);
            kk[j4*4+2]=fmaf(sv,b.z,kk[j4*4+2]); kk[j4*4+3]=fmaf(sv,b.w,kk[j4*4+3]);
            const float4 d = *(const float4*)(wr + 64 + j4*4);
            vv[j4*4+0]=fmaf(sv,d.x,vv[j4*4+0]); vv[j4*4+1]=fmaf(sv,d.y,vv[j4*4+1]);
            vv[j4*4+2]=fmaf(sv,d.z,vv[j4*4+2]); vv[j4*4+3]=fmaf(sv,d.w,vv[j4*4+3]);
        }
    }
    #pragma unroll
    for (int c = 0; c < 32; ++c) { ks[s*36+c] = kk[c]; vs[s*36+c] = vv[c]; }
    __syncthreads();

    const float scale = 1.0f / sqrtf(32.0f);
    float sc[64];
    #pragma unroll
    for (int tt = 0; tt < 64; ++tt) {
        float acc = 0.f;
        #pragma unroll
        for (int c4 = 0; c4 < 8; ++c4) {
            const float4 k4 = *(const float4*)(ks + tt*36 + c4*4);
            acc = fmaf(q[c4*4+0],k4.x,acc); acc = fmaf(q[c4*4+1],k4.y,acc);
            acc = fmaf(q[c4*4+2],k4.z,acc); acc = fmaf(q[c4*4+3],k4.w,acc);
        }
        sc[tt] = acc * scale;
    }
    float m = -1e30f;
    #pragma unroll
    for (int tt = 0; tt < 64; ++tt) m = fmaxf(m, sc[tt]);
    float sum = 0.f;
    #pragma unroll
    for (int tt = 0; tt < 64; ++tt) { sc[tt] = expf(sc[tt]-m); sum += sc[tt]; }
    const float r = 1.0f / sum;
    #pragma unroll
    for (int tt = 0; tt < 64; ++tt) sc[tt] *= r;

    float o[32];
    #pragma unroll
    for (int c = 0; c < 32; ++c) o[c] = 0.f;
    #pragma unroll
    for (int tt = 0; tt < 64; ++tt) {
        const float av = sc[tt];
        #pragma unroll
        for (int c4 = 0; c4 < 8; ++c4) {
            const float4 v4 = *(const float4*)(vs + tt*36 + c4*4);
            o[c4*4+0]=fmaf(av,v4.x,o[c4*4+0]); o[c4*4+1]=fmaf(av,v4.y,o[c4*4+1]);
            o[c4*4+2]=fmaf(av,v4.z,o[c4*4+2]); o[c4*4+3]=fmaf(av,v4.w,o[c4*4+3]);
        }
    }
    float* dst = osl + h*2048 + s*32;
    #pragma unroll
    for (int c = 0; c < 32; ++c) dst[c] = o[c];
}

// =========================================================================
// kD: recompute softmax from midxm, scatter osl (VALU), proj via MFMA.
//     4096 blocks x 64 tokens x 512 thr.
// =========================================================================
__global__ void __launch_bounds__(512, 2) tk_d(
    const unsigned short* __restrict__ midxm,
    const float* __restrict__ Wslc, const float* __restrict__ bslc,
    const float* __restrict__ temp,
    const float* __restrict__ oslg,
    const unsigned short* __restrict__ WprojT,
    const float* __restrict__ bp,
    float* __restrict__ out)
{
    extern __shared__ float sm[];
    float* oslds = sm;                       // [8][2052] fp32
    float* wsl   = sm + 16416;               // [32][64]
    float* bsl   = wsl + 2048;               // [64]
    char*  atile = (char*)(bsl + 64);        // [64][256] bf16, swizzled (32KB)
    char*  btile = atile + 32768;            // [256][64] bf16, swizzled (32KB)

    const int t  = threadIdx.x;
    const int l  = t & 63, wv = t >> 6;      // wave id = output col block
    const int n0 = blockIdx.x * 64;

    for (int i = t; i < 2048; i += 512) wsl[i] = Wslc[i];
    if (t < 64) bsl[t] = bslc[t];
    #pragma unroll
    for (int rr = 0; rr < 32; ++rr) {
        const int idx = rr*512 + t;
        oslds[(idx >> 11)*2052 + (idx & 2047)] = oslg[idx];
    }
    __syncthreads();

    // ---- softmax weights for (token iL, head hL) ----
    const int iL = t >> 3, hL = t & 7;
    const float invT = 1.0f / temp[hL];
    float lg[64];
    compute_w_bf(midxm + (size_t)(n0 + iL)*256 + hL*32, wsl, bsl, invT, lg);

    // ---- scatter: ox[c] = sum_s lg[s] * osl[hL][s][c] ----
    float ox[32];
    #pragma unroll
    for (int c = 0; c < 32; ++c) ox[c] = 0.f;
    const float* obase = oslds + hL*2052;
    #pragma unroll
    for (int s = 0; s < 64; ++s)
        scat_acc(obase + s*32, lg[s], ox);

    // ---- write out_x tile as bf16 A [64 tok][256 ch], swizzled ----
    #pragma unroll
    for (int c0 = 0; c0 < 32; c0 += 8) {
        short8v v;
        #pragma unroll
        for (int j = 0; j < 8; ++j) v[j] = (short)f2bf(ox[c0+j]);
        const int ob = iL*512 + (hL*32 + c0)*2;
        *(short8v*)(atile + (ob ^ ((iL & 7) << 4))) = v;
    }
    __syncthreads();

    // ---- proj: out[64][256] = A @ WprojT^T, K=256 in 4 chunks of 64 ----
    float4v acc[4][2];
    #pragma unroll
    for (int mr = 0; mr < 4; ++mr)
        #pragma unroll
        for (int nr = 0; nr < 2; ++nr)
            acc[mr][nr] = (float4v){0.f, 0.f, 0.f, 0.f};

    const int bn = t >> 1, bh = t & 1;       // B-stage: row, k-half
    for (int c = 0; c < 4; ++c) {
        #pragma unroll
        for (int j = 0; j < 4; ++j) {
            const uint4 u = *(const uint4*)(WprojT + (size_t)bn*256 + c*64 + bh*32 + j*8);
            const int kk = bh*32 + j*8;
            *(uint4*)(btile + ((bn*128 + kk*2) ^ ((bn & 7) << 4))) = u;
        }
        __syncthreads();
        #pragma unroll
        for (int ks = 0; ks < 2; ++ks) {
            short8v a[4], b[2];
            const int kof = (ks*32 + (l >> 4)*8) * 2;
            #pragma unroll
            for (int mr = 0; mr < 4; ++mr) {
                const int m = mr*16 + (l & 15);
                a[mr] = *(const short8v*)(atile + ((m*512 + c*128 + kof) ^ ((m & 7) << 4)));
            }
            #pragma unroll
            for (int nr = 0; nr < 2; ++nr) {
                const int n = wv*32 + nr*16 + (l & 15);
                b[nr] = *(const short8v*)(btile + ((n*128 + kof) ^ ((n & 7) << 4)));
            }
            #pragma unroll
            for (int mr = 0; mr < 4; ++mr)
                #pragma unroll
                for (int nr = 0; nr < 2; ++nr)
                    acc[mr][nr] = __builtin_amdgcn_mfma_f32_16x16x32_bf16(
                        a[mr], b[nr], acc[mr][nr], 0, 0, 0);
        }
        __syncthreads();
    }

    // ---- epilogue: + bias, store fp32 ----
    float bias_n[2];
    #pragma unroll
    for (int nr = 0; nr < 2; ++nr) bias_n[nr] = bp[wv*32 + nr*16 + (l & 15)];
    #pragma unroll
    for (int mr = 0; mr < 4; ++mr) {
        #pragma unroll
        for (int reg = 0; reg < 4; ++reg) {
            const int row = n0 + mr*16 + (l >> 4)*4 + reg;
            #pragma unroll
            for (int nr = 0; nr < 2; ++nr) {
                const int col = wv*32 + nr*16 + (l & 15);
                out[(size_t)row*256 + col] = acc[mr][nr][reg] + bias_n[nr];
            }
        }
    }
}

// =========================================================================
extern "C" void kernel_launch(void* const* d_in, const int* in_sizes, int n_in,
                              void* d_out, int out_size, void* d_ws, size_t ws_size,
                              hipStream_t stream)
{
    const float* x     = (const float*)d_in[0];
    const float* Wfx   = (const float*)d_in[1];
    const float* bfx   = (const float*)d_in[2];
    const float* Wx    = (const float*)d_in[3];
    const float* bx    = (const float*)d_in[4];
    const float* Wslc  = (const float*)d_in[5];
    const float* bslc  = (const float*)d_in[6];
    const float* Wqkv  = (const float*)d_in[7];
    const float* Wproj = (const float*)d_in[8];
    const float* bproj = (const float*)d_in[9];
    const float* temp  = (const float*)d_in[10];

    char* wsb = (char*)d_ws;
    unsigned short* midfx  = (unsigned short*)(wsb + OFF_MIDFX);
    unsigned short* midxm  = (unsigned short*)(wsb + OFF_MIDXM);
    unsigned short* WcatT  = (unsigned short*)(wsb + OFF_WCT);
    unsigned short* WprojT = (unsigned short*)(wsb + OFF_WPT);
    float* poolp = (float*)(wsb + OFF_POOLP);
    float* normp = (float*)(wsb + OFF_NORMP);
    float* ssum  = (float*)(wsb + OFF_SSUM);
    float* nsum  = (float*)(wsb + OFF_NSUM);
    float* osl   = (float*)(wsb + OFF_OSL);
    float* out   = (float*)d_out;

    (void)hipFuncSetAttribute((const void*)tk_a, hipFuncAttributeMaxDynamicSharedMemorySize, KA_LDS_B);
    (void)hipFuncSetAttribute((const void*)tk_b, hipFuncAttributeMaxDynamicSharedMemorySize, KB_LDS_F*4);
    (void)hipFuncSetAttribute((const void*)tk_d, hipFuncAttributeMaxDynamicSharedMemorySize, KD_LDS_B);

    tk_w<<<24, 512, 0, stream>>>(Wfx, Wx, Wproj, WcatT, WprojT);
    tk_a<<<2048, 512, KA_LDS_B, stream>>>(x, WcatT, bfx, bx, midfx, midxm);
    tk_b<<<512, 512, KB_LDS_F*4, stream>>>(midfx, midxm, Wslc, bslc, temp, poolp, normp);
    tk_2a<<<66, 256, 0, stream>>>(poolp, normp, ssum, nsum);
    tk_2b<<<8, 64, 0, stream>>>(ssum, nsum, Wqkv, osl);
    tk_d<<<4096, 512, KD_LDS_B, stream>>>(midxm, Wslc, bslc, temp, osl, WprojT, bproj, out);
}

// Round 8
// 1950.533 us; speedup vs baseline: 1.1455x; 1.1455x over previous
//
#include <hip/hip_runtime.h>
#include <math.h>

#define NTOK 262144
#define DIM  256
#define NH   8
#define CH   32
#define NS   64

typedef __attribute__((ext_vector_type(8))) short short8v;   // 8 bf16 = 4 VGPR
typedef __attribute__((ext_vector_type(4))) float float4v;

// ---------------- workspace layout (bytes) ----------------
constexpr size_t OFF_MID   = 0;                          // N*512 bf16 = 268435456
constexpr size_t OFF_WCT   = 268435456;                  // 512*256 bf16 = 262144
constexpr size_t OFF_POOLP = OFF_WCT + 262144;           // 512*16384 f32 = 33554432
constexpr size_t OFF_NORMP = OFF_POOLP + 33554432;       // 512*512 f32 = 1048576
constexpr size_t OFF_SSUM  = OFF_NORMP + 1048576;        // 16384 f32
constexpr size_t OFF_NSUM  = OFF_SSUM + 65536;           // 512 f32
constexpr size_t OFF_OPT   = OFF_NSUM + 2048;            // 256*512 bf16 = 262144

#define KA_LDS_B 81920                        // A 128x64 (16KB) + B 512x64 (64KB)
#define KB_LDS_F (18432 + 2048 + 64)          // wls[512][36] + Wslc + bsl (round-5 exact)
#define KD_LDS_B (65536 + 65536 + 8192 + 256) // A 64KB + 2x bstage 32KB + wsl + bsl = 139520

__device__ __forceinline__ unsigned short f2bf(float f) {
    unsigned u = __float_as_uint(f);
    unsigned r = (u + 0x7fffu + ((u >> 16) & 1u)) >> 16;   // RNE
    return (unsigned short)r;
}
__device__ __forceinline__ float bf2f(unsigned short u) {
    return __uint_as_float(((unsigned)u) << 16);
}

// ---- logits+softmax from bf16 x_mid row: lg[64] = softmax((xm@Wslc+b)/temp) ----
__device__ __forceinline__ void compute_w_bf(const unsigned short* __restrict__ xm,
                                             const float* __restrict__ wsl,
                                             const float* __restrict__ bsl,
                                             float invT, float* lg)
{
    float xv[32];
    #pragma unroll
    for (int q = 0; q < 4; ++q) {
        const uint4 u = *(const uint4*)(xm + q*8);
        const unsigned vals[4] = {u.x, u.y, u.z, u.w};
        #pragma unroll
        for (int j = 0; j < 4; ++j) {
            xv[q*8 + j*2 + 0] = __uint_as_float(vals[j] << 16);
            xv[q*8 + j*2 + 1] = __uint_as_float(vals[j] & 0xffff0000u);
        }
    }
    #pragma unroll
    for (int s = 0; s < 64; ++s) lg[s] = bsl[s];
    #pragma unroll
    for (int c = 0; c < 32; ++c) {
        const float xvj = xv[c];
        const float* wr = wsl + c*64;
        #pragma unroll
        for (int s4 = 0; s4 < 16; ++s4) {
            const float4 w4 = *(const float4*)(wr + s4*4);
            lg[s4*4+0] = fmaf(xvj, w4.x, lg[s4*4+0]);
            lg[s4*4+1] = fmaf(xvj, w4.y, lg[s4*4+1]);
            lg[s4*4+2] = fmaf(xvj, w4.z, lg[s4*4+2]);
            lg[s4*4+3] = fmaf(xvj, w4.w, lg[s4*4+3]);
        }
    }
    float m = -1e30f;
    #pragma unroll
    for (int s = 0; s < 64; ++s) { lg[s] *= invT; m = fmaxf(m, lg[s]); }
    float sum = 0.f;
    #pragma unroll
    for (int s = 0; s < 64; ++s) { lg[s] = expf(lg[s] - m); sum += lg[s]; }
    const float r = 1.0f / sum;
    #pragma unroll
    for (int s = 0; s < 64; ++s) lg[s] *= r;
}

// =========================================================================
// kW: WcatT[512][256] = [Wfx|Wx]^T in bf16. Grid 16 x 512.
// =========================================================================
__global__ void __launch_bounds__(512) tk_w(
    const float* __restrict__ Wfx, const float* __restrict__ Wx,
    unsigned short* __restrict__ WcatT)
{
    const int t = threadIdx.x, b = blockIdx.x;
    const int rl = t >> 4, q = t & 15;
    const int r = b*32 + rl;            // 0..511
    #pragma unroll
    for (int j = 0; j < 16; ++j) {
        const int k = q*16 + j;
        const float v = (r < 256) ? Wfx[(size_t)k*256 + r] : Wx[(size_t)k*256 + (r-256)];
        WcatT[(size_t)r*256 + k] = f2bf(v);
    }
}

// =========================================================================
// kA: mid[N][512] (bf16) = x @ [Wfx|Wx] + bias, via 16x16x32 bf16 MFMA.
//     2048 blocks x 512 thr; tile 128 x 512, K=256 in 4 chunks of 64.
//     (round-5 proven version)
// =========================================================================
__global__ void __launch_bounds__(512, 2) tk_a(
    const float* __restrict__ x,
    const unsigned short* __restrict__ WcatT,
    const float* __restrict__ bfx, const float* __restrict__ bx,
    unsigned short* __restrict__ midp)
{
    extern __shared__ char smem[];
    char* astage = smem;              // [128][64] bf16, swizzled
    char* bstage = smem + 16384;      // [512][64] bf16, swizzled

    const int t = threadIdx.x;
    const int l = t & 63, w = t >> 6;
    const int wm = w >> 2, wn = w & 3;
    const int m0 = blockIdx.x * 128;

    float4v acc[4][8];
    #pragma unroll
    for (int mr = 0; mr < 4; ++mr)
        #pragma unroll
        for (int nr = 0; nr < 8; ++nr)
            acc[mr][nr] = (float4v){0.f, 0.f, 0.f, 0.f};

    const int ar = t >> 2, aq = t & 3;

    for (int c = 0; c < 4; ++c) {
        {
            const float* xr = x + (size_t)(m0 + ar)*256 + c*64 + aq*16;
            const float4 f0 = *(const float4*)(xr + 0);
            const float4 f1 = *(const float4*)(xr + 4);
            const float4 f2 = *(const float4*)(xr + 8);
            const float4 f3 = *(const float4*)(xr + 12);
            short8v v0, v1;
            v0[0]=(short)f2bf(f0.x); v0[1]=(short)f2bf(f0.y); v0[2]=(short)f2bf(f0.z); v0[3]=(short)f2bf(f0.w);
            v0[4]=(short)f2bf(f1.x); v0[5]=(short)f2bf(f1.y); v0[6]=(short)f2bf(f1.z); v0[7]=(short)f2bf(f1.w);
            v1[0]=(short)f2bf(f2.x); v1[1]=(short)f2bf(f2.y); v1[2]=(short)f2bf(f2.z); v1[3]=(short)f2bf(f2.w);
            v1[4]=(short)f2bf(f3.x); v1[5]=(short)f2bf(f3.y); v1[6]=(short)f2bf(f3.z); v1[7]=(short)f2bf(f3.w);
            const int ob = ar*128 + aq*32;
            *(short8v*)(astage + ((ob     ) ^ ((ar & 7) << 4))) = v0;
            *(short8v*)(astage + ((ob + 16) ^ ((ar & 7) << 4))) = v1;
        }
        {
            const int n = t;
            #pragma unroll
            for (int j = 0; j < 8; ++j) {
                const uint4 u = *(const uint4*)(WcatT + (size_t)n*256 + c*64 + j*8);
                *(uint4*)(bstage + ((n*128 + j*16) ^ ((n & 7) << 4))) = u;
            }
        }
        __syncthreads();
        #pragma unroll
        for (int ks = 0; ks < 2; ++ks) {
            short8v a[4], b[8];
            const int kof = (ks*32 + (l >> 4)*8) * 2;
            #pragma unroll
            for (int mr = 0; mr < 4; ++mr) {
                const int m = wm*64 + mr*16 + (l & 15);
                a[mr] = *(const short8v*)(astage + ((m*128 + kof) ^ ((m & 7) << 4)));
            }
            #pragma unroll
            for (int nr = 0; nr < 8; ++nr) {
                const int n = wn*128 + nr*16 + (l & 15);
                b[nr] = *(const short8v*)(bstage + ((n*128 + kof) ^ ((n & 7) << 4)));
            }
            #pragma unroll
            for (int mr = 0; mr < 4; ++mr)
                #pragma unroll
                for (int nr = 0; nr < 8; ++nr)
                    acc[mr][nr] = __builtin_amdgcn_mfma_f32_16x16x32_bf16(
                        a[mr], b[nr], acc[mr][nr], 0, 0, 0);
        }
        __syncthreads();
    }

    float bias_n[8];
    #pragma unroll
    for (int nr = 0; nr < 8; ++nr) {
        const int col = wn*128 + nr*16 + (l & 15);
        bias_n[nr] = (col < 256) ? bfx[col] : bx[col - 256];
    }
    #pragma unroll
    for (int mr = 0; mr < 4; ++mr) {
        #pragma unroll
        for (int reg = 0; reg < 4; ++reg) {
            const int row = m0 + wm*64 + mr*16 + (l >> 4)*4 + reg;
            #pragma unroll
            for (int nr = 0; nr < 8; ++nr) {
                const int col = wn*128 + nr*16 + (l & 15);
                midp[(size_t)row*512 + col] = f2bf(acc[mr][nr][reg] + bias_n[nr]);
            }
        }
    }
}

// =========================================================================
// kB: logits+softmax+pool partials from mid. 512 blocks x 8 tiles x 64 tok.
//     (round-5 proven version)
// =========================================================================
__global__ void __launch_bounds__(512, 2) tk_b(
    const unsigned short* __restrict__ midp,
    const float* __restrict__ Wslc, const float* __restrict__ bslc,
    const float* __restrict__ temp,
    float* __restrict__ poolp, float* __restrict__ normp)
{
    extern __shared__ float sm[];
    float* wls = sm;            // [512 rows][36]  (18432 f)
    float* wsl = sm + 18432;    // W_slice [32][64]
    float* bsl = wsl + 2048;    // b_slice [64]

    const int t   = threadIdx.x;
    const int blk = blockIdx.x;

    for (int i = t; i < 2048; i += 512) wsl[i] = Wslc[i];
    if (t < 64) bsl[t] = bslc[t];
    __syncthreads();

    const int cg = t & 255, ihalf = t >> 8;
    const int hP = cg >> 5;
    const int cP = cg & 31;
    const int iL = t >> 3,   hL = t & 7;
    const int hN = t >> 6;
    const int sN = (t >> 1) & 31, iqN = t & 1;

    float pool[64];
    #pragma unroll
    for (int s = 0; s < 64; ++s) pool[s] = 0.f;
    float nacc0 = 0.f, nacc1 = 0.f;

    const float invT = 1.0f / temp[hL];

    for (int tl = 0; tl < 8; ++tl) {
        const int n0 = blk*512 + tl*64;

        float afx[32];
        #pragma unroll
        for (int ii = 0; ii < 32; ++ii)
            afx[ii] = bf2f(midp[(size_t)(n0 + ihalf*32 + ii)*512 + cg]);

        float lg[64];
        compute_w_bf(midp + (size_t)(n0 + iL)*512 + 256 + hL*32, wsl, bsl, invT, lg);

        #pragma unroll
        for (int sh = 0; sh < 2; ++sh) {
            float* wrow = wls + t*36;
            #pragma unroll
            for (int sl = 0; sl < 32; sl += 2)
                *(float2*)(wrow + sl) = make_float2(lg[sh*32+sl], lg[sh*32+sl+1]);
            __syncthreads();
            #pragma unroll
            for (int ii = 0; ii < 32; ++ii) {
                const float fxv = afx[ii];
                const float* wr2 = wls + ((ihalf*32+ii)*8 + hP)*36;
                #pragma unroll
                for (int s4 = 0; s4 < 8; ++s4) {
                    const float4 w4 = *(const float4*)(wr2 + s4*4);
                    pool[sh*32+s4*4+0] = fmaf(fxv, w4.x, pool[sh*32+s4*4+0]);
                    pool[sh*32+s4*4+1] = fmaf(fxv, w4.y, pool[sh*32+s4*4+1]);
                    pool[sh*32+s4*4+2] = fmaf(fxv, w4.z, pool[sh*32+s4*4+2]);
                    pool[sh*32+s4*4+3] = fmaf(fxv, w4.w, pool[sh*32+s4*4+3]);
                }
            }
            {
                float na = 0.f;
                #pragma unroll
                for (int ii = 0; ii < 32; ++ii)
                    na += wls[((iqN*32+ii)*8 + hN)*36 + sN];
                if (sh == 0) nacc0 += na; else nacc1 += na;
            }
            __syncthreads();
        }
    }

    if (ihalf == 1) {
        float* buf = wls + cg*65;
        #pragma unroll
        for (int s = 0; s < 64; ++s) buf[s] = pool[s];
    }
    if (iqN == 1) {
        wls[16640 + (hN*32+sN)*2 + 0] = nacc0;
        wls[16640 + (hN*32+sN)*2 + 1] = nacc1;
    }
    __syncthreads();
    if (ihalf == 0) {
        const float* buf = wls + cg*65;
        float* dst = poolp + (size_t)blk*(NH*NS*CH) + (size_t)hP*(NS*CH) + cP;
        #pragma unroll
        for (int s = 0; s < 64; ++s) dst[(size_t)s*CH] = pool[s] + buf[s];
    }
    if (iqN == 0) {
        const float v0 = nacc0 + wls[16640 + (hN*32+sN)*2 + 0];
        const float v1 = nacc1 + wls[16640 + (hN*32+sN)*2 + 1];
        normp[(size_t)blk*512 + hN*64 + sN]      = v0;
        normp[(size_t)blk*512 + hN*64 + 32 + sN] = v1;
    }
}

// =========================================================================
// k2a: reduce 512 per-block partials -> slice sums + norms
// =========================================================================
__global__ void __launch_bounds__(256) tk_2a(
    const float* __restrict__ poolp, const float* __restrict__ normp,
    float* __restrict__ ssum, float* __restrict__ nsum)
{
    const int idx = blockIdx.x*256 + threadIdx.x;
    if (idx < 16384) {
        float a0=0.f,a1=0.f,a2=0.f,a3=0.f;
        for (int b = 0; b < 512; b += 4) {
            a0 += poolp[(size_t)(b+0)*16384 + idx];
            a1 += poolp[(size_t)(b+1)*16384 + idx];
            a2 += poolp[(size_t)(b+2)*16384 + idx];
            a3 += poolp[(size_t)(b+3)*16384 + idx];
        }
        ssum[idx] = (a0+a1)+(a2+a3);
    } else if (idx < 16896) {
        const int j = idx - 16384;
        float a0=0.f,a1=0.f,a2=0.f,a3=0.f;
        for (int b = 0; b < 512; b += 4) {
            a0 += normp[(size_t)(b+0)*512 + j];
            a1 += normp[(size_t)(b+1)*512 + j];
            a2 += normp[(size_t)(b+2)*512 + j];
            a3 += normp[(size_t)(b+3)*512 + j];
        }
        nsum[j] = (a0+a1)+(a2+a3);
    }
}

// =========================================================================
// k2b: slice tokens -> qkv -> SDPA -> out_slice -> FUSED with Wproj:
//      OPT[p][h*64+s] = sum_c out_slice[h][s][c] * Wproj[h*32+c][p]  (bf16)
//      1 block/head, 64 threads (s).
// =========================================================================
__global__ void __launch_bounds__(64) tk_2b(
    const float* __restrict__ ssum, const float* __restrict__ nsum,
    const float* __restrict__ Wqkv, const float* __restrict__ Wproj,
    unsigned short* __restrict__ opt)
{
    __shared__ float ks[64*36];
    __shared__ float vs[64*36];
    const int h = blockIdx.x;
    const int s = threadIdx.x;

    const float inv = 1.0f / (nsum[h*64 + s] + 1e-5f);
    const float* st = ssum + h*2048 + s*32;

    float q[32], kk[32], vv[32];
    #pragma unroll
    for (int j = 0; j < 32; ++j) { q[j]=0.f; kk[j]=0.f; vv[j]=0.f; }
    for (int c = 0; c < 32; ++c) {
        const float sv = st[c] * inv;
        const float* wr = Wqkv + c*96;
        #pragma unroll
        for (int j4 = 0; j4 < 8; ++j4) {
            const float4 a = *(const float4*)(wr + j4*4);
            q[j4*4+0]=fmaf(sv,a.x,q[j4*4+0]); q[j4*4+1]=fmaf(sv,a.y,q[j4*4+1]);
            q[j4*4+2]=fmaf(sv,a.z,q[j4*4+2]); q[j4*4+3]=fmaf(sv,a.w,q[j4*4+3]);
            const float4 b = *(const float4*)(wr + 32 + j4*4);
            kk[j4*4+0]=fmaf(sv,b.x,kk[j4*4+0]); kk[j4*4+1]=fmaf(sv,b.y,kk[j4*4+1]);
            kk[j4*4+2]=fmaf(sv,b.z,kk[j4*4+2]); kk[j4*4+3]=fmaf(sv,b.w,kk[j4*4+3]);
            const float4 d = *(const float4*)(wr + 64 + j4*4);
            vv[j4*4+0]=fmaf(sv,d.x,vv[j4*4+0]); vv[j4*4+1]=fmaf(sv,d.y,vv[j4*4+1]);
            vv[j4*4+2]=fmaf(sv,d.z,vv[j4*4+2]); vv[j4*4+3]=fmaf(sv,d.w,vv[j4*4+3]);
        }
    }
    #pragma unroll
    for (int c = 0; c < 32; ++c) { ks[s*36+c] = kk[c]; vs[s*36+c] = vv[c]; }
    __syncthreads();

    const float scale = 1.0f / sqrtf(32.0f);
    float sc[64];
    #pragma unroll
    for (int tt = 0; tt < 64; ++tt) {
        float acc = 0.f;
        #pragma unroll
        for (int c4 = 0; c4 < 8; ++c4) {
            const float4 k4 = *(const float4*)(ks + tt*36 + c4*4);
            acc = fmaf(q[c4*4+0],k4.x,acc); acc = fmaf(q[c4*4+1],k4.y,acc);
            acc = fmaf(q[c4*4+2],k4.z,acc); acc = fmaf(q[c4*4+3],k4.w,acc);
        }
        sc[tt] = acc * scale;
    }
    float m = -1e30f;
    #pragma unroll
    for (int tt = 0; tt < 64; ++tt) m = fmaxf(m, sc[tt]);
    float sum = 0.f;
    #pragma unroll
    for (int tt = 0; tt < 64; ++tt) { sc[tt] = expf(sc[tt]-m); sum += sc[tt]; }
    const float r = 1.0f / sum;
    #pragma unroll
    for (int tt = 0; tt < 64; ++tt) sc[tt] *= r;

    float o[32];
    #pragma unroll
    for (int c = 0; c < 32; ++c) o[c] = 0.f;
    #pragma unroll
    for (int tt = 0; tt < 64; ++tt) {
        const float av = sc[tt];
        #pragma unroll
        for (int c4 = 0; c4 < 8; ++c4) {
            const float4 v4 = *(const float4*)(vs + tt*36 + c4*4);
            o[c4*4+0]=fmaf(av,v4.x,o[c4*4+0]); o[c4*4+1]=fmaf(av,v4.y,o[c4*4+1]);
            o[c4*4+2]=fmaf(av,v4.z,o[c4*4+2]); o[c4*4+3]=fmaf(av,v4.w,o[c4*4+3]);
        }
    }

    // ---- fused out_slice @ Wproj-slice -> OPT (transposed, bf16) ----
    for (int pc = 0; pc < 4; ++pc) {
        float op[64];
        #pragma unroll
        for (int j = 0; j < 64; ++j) op[j] = 0.f;
        for (int c = 0; c < 32; ++c) {
            const float oc = o[c];
            const float* wr = Wproj + (size_t)(h*32 + c)*256 + pc*64;
            #pragma unroll
            for (int j4 = 0; j4 < 16; ++j4) {
                const float4 w4 = *(const float4*)(wr + j4*4);
                op[j4*4+0] = fmaf(oc, w4.x, op[j4*4+0]);
                op[j4*4+1] = fmaf(oc, w4.y, op[j4*4+1]);
                op[j4*4+2] = fmaf(oc, w4.z, op[j4*4+2]);
                op[j4*4+3] = fmaf(oc, w4.w, op[j4*4+3]);
            }
        }
        #pragma unroll
        for (int j = 0; j < 64; ++j)
            opt[(size_t)(pc*64 + j)*512 + h*64 + s] = f2bf(op[j]);
    }
}

// =========================================================================
// kD: recompute softmax from mid.xm -> w (bf16, LDS A-tile) ->
//     out[64 tok][256] = w[64][512] @ OPT^T + bproj  (merged scatter+proj).
//     4096 blocks x 512 thr; K=512 in 8 chunks of 64, double-buffered B.
// =========================================================================
__global__ void __launch_bounds__(512, 2) tk_d(
    const unsigned short* __restrict__ midp,
    const float* __restrict__ Wslc, const float* __restrict__ bslc,
    const float* __restrict__ temp,
    const unsigned short* __restrict__ optg,
    const float* __restrict__ bp,
    float* __restrict__ out)
{
    extern __shared__ char smem[];
    char*  alds = smem;                      // [64 tok][1024B] bf16, XOR-swizzled
    char*  bst  = smem + 65536;              // 2 x [256 p][128B] bf16, XOR-swizzled
    float* wsl  = (float*)(smem + 131072);   // [2048]
    float* bsl  = wsl + 2048;                // [64]

    const int t = threadIdx.x;
    const int l = t & 63, wv = t >> 6;
    const int n0 = blockIdx.x * 64;

    for (int i = t; i < 2048; i += 512) wsl[i] = Wslc[i];
    if (t < 64) bsl[t] = bslc[t];

    // stage OPT chunk kc=0 into buf 0
    const int sp = t >> 1, shalf = t & 1;
    {
        const unsigned short* src = optg + (size_t)sp*512 + shalf*32;
        #pragma unroll
        for (int j = 0; j < 4; ++j) {
            const uint4 u = *(const uint4*)(src + j*8);
            const int off = shalf*64 + j*16;
            *(uint4*)(bst + sp*128 + (off ^ ((sp & 7) << 4))) = u;
        }
    }
    __syncthreads();

    // ---- softmax weights for (token iL, head hL), fp32 (unchanged math) ----
    const int iL = t >> 3, hL = t & 7;
    const float invT = 1.0f / temp[hL];
    float lg[64];
    compute_w_bf(midp + (size_t)(n0 + iL)*512 + 256 + hL*32, wsl, bsl, invT, lg);

    // ---- write w -> A_lds row iL, cols hL*64..+63 (bf16), swizzled ----
    #pragma unroll
    for (int j = 0; j < 8; ++j) {
        short8v v;
        #pragma unroll
        for (int e = 0; e < 8; ++e) v[e] = (short)f2bf(lg[j*8+e]);
        const int off = hL*128 + j*16;
        *(short8v*)(alds + iL*1024 + (off ^ ((iL & 7) << 4))) = v;
    }
    __syncthreads();

    // ---- GEMM: out[64][256] = A(w) @ OPT^T, K=512 ----
    float4v acc[4][2];
    #pragma unroll
    for (int mr = 0; mr < 4; ++mr)
        #pragma unroll
        for (int nr = 0; nr < 2; ++nr)
            acc[mr][nr] = (float4v){0.f, 0.f, 0.f, 0.f};

    int buf = 0;
    for (int kc = 0; kc < 8; ++kc) {
        if (kc < 7) {
            const unsigned short* src = optg + (size_t)sp*512 + (kc+1)*64 + shalf*32;
            char* bdst = bst + (buf^1)*32768;
            #pragma unroll
            for (int j = 0; j < 4; ++j) {
                const uint4 u = *(const uint4*)(src + j*8);
                const int off = shalf*64 + j*16;
                *(uint4*)(bdst + sp*128 + (off ^ ((sp & 7) << 4))) = u;
            }
        }
        const char* bcur = bst + buf*32768;
        #pragma unroll
        for (int ksi = 0; ksi < 2; ++ksi) {
            short8v a[4], b[2];
            #pragma unroll
            for (int mr = 0; mr < 4; ++mr) {
                const int row = mr*16 + (l & 15);
                const int off = kc*128 + ksi*64 + (l >> 4)*16;
                a[mr] = *(const short8v*)(alds + row*1024 + (off ^ ((row & 7) << 4)));
            }
            #pragma unroll
            for (int nr = 0; nr < 2; ++nr) {
                const int n = wv*32 + nr*16 + (l & 15);
                const int off = ksi*64 + (l >> 4)*16;
                b[nr] = *(const short8v*)(bcur + n*128 + (off ^ ((n & 7) << 4)));
            }
            #pragma unroll
            for (int mr = 0; mr < 4; ++mr)
                #pragma unroll
                for (int nr = 0; nr < 2; ++nr)
                    acc[mr][nr] = __builtin_amdgcn_mfma_f32_16x16x32_bf16(
                        a[mr], b[nr], acc[mr][nr], 0, 0, 0);
        }
        __syncthreads();
        buf ^= 1;
    }

    // ---- epilogue: + bias, store fp32 ----
    float bias_n[2];
    #pragma unroll
    for (int nr = 0; nr < 2; ++nr) bias_n[nr] = bp[wv*32 + nr*16 + (l & 15)];
    #pragma unroll
    for (int mr = 0; mr < 4; ++mr) {
        #pragma unroll
        for (int reg = 0; reg < 4; ++reg) {
            const int row = n0 + mr*16 + (l >> 4)*4 + reg;
            #pragma unroll
            for (int nr = 0; nr < 2; ++nr) {
                const int col = wv*32 + nr*16 + (l & 15);
                out[(size_t)row*256 + col] = acc[mr][nr][reg] + bias_n[nr];
            }
        }
    }
}

// =========================================================================
extern "C" void kernel_launch(void* const* d_in, const int* in_sizes, int n_in,
                              void* d_out, int out_size, void* d_ws, size_t ws_size,
                              hipStream_t stream)
{
    const float* x     = (const float*)d_in[0];
    const float* Wfx   = (const float*)d_in[1];
    const float* bfx   = (const float*)d_in[2];
    const float* Wx    = (const float*)d_in[3];
    const float* bx    = (const float*)d_in[4];
    const float* Wslc  = (const float*)d_in[5];
    const float* bslc  = (const float*)d_in[6];
    const float* Wqkv  = (const float*)d_in[7];
    const float* Wproj = (const float*)d_in[8];
    const float* bproj = (const float*)d_in[9];
    const float* temp  = (const float*)d_in[10];

    char* wsb = (char*)d_ws;
    unsigned short* midp  = (unsigned short*)(wsb + OFF_MID);
    unsigned short* WcatT = (unsigned short*)(wsb + OFF_WCT);
    float* poolp = (float*)(wsb + OFF_POOLP);
    float* normp = (float*)(wsb + OFF_NORMP);
    float* ssum  = (float*)(wsb + OFF_SSUM);
    float* nsum  = (float*)(wsb + OFF_NSUM);
    unsigned short* opt = (unsigned short*)(wsb + OFF_OPT);
    float* out   = (float*)d_out;

    (void)hipFuncSetAttribute((const void*)tk_a, hipFuncAttributeMaxDynamicSharedMemorySize, KA_LDS_B);
    (void)hipFuncSetAttribute((const void*)tk_b, hipFuncAttributeMaxDynamicSharedMemorySize, KB_LDS_F*4);
    (void)hipFuncSetAttribute((const void*)tk_d, hipFuncAttributeMaxDynamicSharedMemorySize, KD_LDS_B);

    tk_w<<<16, 512, 0, stream>>>(Wfx, Wx, WcatT);
    tk_a<<<2048, 512, KA_LDS_B, stream>>>(x, WcatT, bfx, bx, midp);
    tk_b<<<512, 512, KB_LDS_F*4, stream>>>(midp, Wslc, bslc, temp, poolp, normp);
    tk_2a<<<66, 256, 0, stream>>>(poolp, normp, ssum, nsum);
    tk_2b<<<8, 64, 0, stream>>>(ssum, nsum, Wqkv, Wproj, opt);
    tk_d<<<4096, 512, KD_LDS_B, stream>>>(midp, Wslc, bslc, temp, opt, bproj, out);
}